// Round 6
// baseline (156.495 us; speedup 1.0000x reference)
//
#include <hip/hip_runtime.h>

// YOLO loss: per-cell masked squared-error reduction over [B,7,7,30] fp32 x2.
// Per cell: mask = (gt[...,4] == 1.0)
//   per_cell = mask ? 5*sum((pre[0:4]-gt[0:4])^2) + 10*(pre[4]-gt[4])^2
//                   : 0.5*(pre[4]-gt[4])^2
// Output: scalar sum, shape (1,).
//
// Layout: 2-cell period = 60 floats = 240 B. Needed channels (0..4 per cell)
// live in two 32 B-contiguous, 16 B-aligned spans per period:
//   cell0: bytes [q*240 +  0, +32)  -> coords A.xyzw, conf B.x
//   cell1: bytes [q*240 +112, +144) -> coords {A.z,A.w,B.x,B.y}, conf B.z
// One lane per cell, two aligned float4 loads per buffer, lane-local mask.
// R6: non-temporal loads via clang native vector type (HIP_vector_type is
// rejected by __builtin_nontemporal_load) + unroll x2, split accumulators.

typedef float f32x4 __attribute__((ext_vector_type(4)));

__global__ __launch_bounds__(256) void yolo_loss_kernel(
    const float* __restrict__ pre,
    const float* __restrict__ gt,
    float* __restrict__ out,
    unsigned int n_cells)
{
    unsigned int tid    = blockIdx.x * blockDim.x + threadIdx.x;
    unsigned int stride = gridDim.x * blockDim.x;   // even -> (m&1) const/thread

    const bool hi = (tid & 1u);   // stride is even: parity fixed per thread

    auto cell_term = [&](unsigned int m) -> float {
        size_t base = (size_t)(m >> 1) * 60 + (hi ? 28 : 0);  // 16B-aligned
        const f32x4 pa = __builtin_nontemporal_load(
            reinterpret_cast<const f32x4*>(pre + base));
        const f32x4 pb = __builtin_nontemporal_load(
            reinterpret_cast<const f32x4*>(pre + base + 4));
        const f32x4 ga = __builtin_nontemporal_load(
            reinterpret_cast<const f32x4*>(gt + base));
        const f32x4 gb = __builtin_nontemporal_load(
            reinterpret_cast<const f32x4*>(gt + base + 4));

        float p0 = hi ? pa.z : pa.x;
        float p1 = hi ? pa.w : pa.y;
        float p2 = hi ? pb.x : pa.z;
        float p3 = hi ? pb.y : pa.w;
        float pc = hi ? pb.z : pb.x;
        float g0 = hi ? ga.z : ga.x;
        float g1 = hi ? ga.w : ga.y;
        float g2 = hi ? gb.x : ga.z;
        float g3 = hi ? gb.y : ga.w;
        float gc = hi ? gb.z : gb.x;

        float d0 = p0 - g0, d1 = p1 - g1, d2 = p2 - g2, d3 = p3 - g3;
        float dc = pc - gc;
        float coord = d0 * d0 + d1 * d1 + d2 * d2 + d3 * d3;
        float conf  = dc * dc;
        return (gc == 1.0f) ? fmaf(5.0f, coord, 10.0f * conf) : 0.5f * conf;
    };

    float acc0 = 0.0f, acc1 = 0.0f;
    unsigned int m = tid;
    // unrolled x2: 8 independent loads in flight per iteration
    for (; m + stride < n_cells; m += 2 * stride) {
        acc0 += cell_term(m);
        acc1 += cell_term(m + stride);
    }
    if (m < n_cells) acc0 += cell_term(m);

    float acc = acc0 + acc1;

    // wave-64 shuffle-down reduction
    for (int offr = 32; offr > 0; offr >>= 1)
        acc += __shfl_down(acc, offr, 64);

    __shared__ float s[4];
    int lane = threadIdx.x & 63;
    int wid  = threadIdx.x >> 6;
    if (lane == 0) s[wid] = acc;
    __syncthreads();

    if (threadIdx.x == 0) {
        float total = s[0] + s[1] + s[2] + s[3];
        atomicAdd(out, total);   // device-scope by default on CDNA
    }
}

extern "C" void kernel_launch(void* const* d_in, const int* in_sizes, int n_in,
                              void* d_out, int out_size, void* d_ws, size_t ws_size,
                              hipStream_t stream) {
    const float* pre = (const float*)d_in[0];
    const float* gt  = (const float*)d_in[1];
    float* out = (float*)d_out;

    // d_out is poisoned once and never re-poisoned between replays: zero it
    // ourselves every call (stream op — graph-capture safe).
    (void)hipMemsetAsync(out, 0, sizeof(float), stream);

    unsigned int n_cells = (unsigned int)((long long)in_sizes[0] / 30);  // 3,211,264

    const int block = 256;
    const int grid  = 2048;   // 8192 waves = max residency; ~6.1 cells/thread
    yolo_loss_kernel<<<grid, block, 0, stream>>>(pre, gt, out, n_cells);
}

// Round 7
// 146.443 us; speedup vs baseline: 1.0686x; 1.0686x over previous
//
#include <hip/hip_runtime.h>

// YOLO loss: per-cell masked squared-error reduction over [B,7,7,30] fp32 x2.
// Per cell: mask = (gt[...,4] == 1.0)
//   per_cell = mask ? 5*sum((pre[0:4]-gt[0:4])^2) + 10*(pre[4]-gt[4])^2
//                   : 0.5*(pre[4]-gt[4])^2
// Output: scalar sum, shape (1,).
//
// R7: one thread per 2-cell PERIOD (60 floats = 240 B). Needed channels sit
// at STATIC float offsets off one base (16 B-aligned):
//   +0  : cell0 coords x,y,z,w
//   +4  : cell0 conf (.x)
//   +28 : cell1 coords 0,1 (.z,.w)
//   +32 : cell1 coords 2,3 (.x,.y) + conf (.z)
// -> 8 independent float4 loads per iteration (natural 8-deep MLP), zero
// parity selects, zero shuffles, zero divergent fixups. ~3 iters/thread.

__global__ __launch_bounds__(256) void yolo_loss_kernel(
    const float* __restrict__ pre,
    const float* __restrict__ gt,
    float* __restrict__ out,
    unsigned int n_periods)
{
    unsigned int tid    = blockIdx.x * blockDim.x + threadIdx.x;
    unsigned int stride = gridDim.x * blockDim.x;

    float acc = 0.0f;
    for (unsigned int q = tid; q < n_periods; q += stride) {
        size_t base = (size_t)q * 60;

        const float4 pA = *reinterpret_cast<const float4*>(pre + base);
        const float4 pB = *reinterpret_cast<const float4*>(pre + base + 4);
        const float4 pC = *reinterpret_cast<const float4*>(pre + base + 28);
        const float4 pD = *reinterpret_cast<const float4*>(pre + base + 32);
        const float4 gA = *reinterpret_cast<const float4*>(gt  + base);
        const float4 gB = *reinterpret_cast<const float4*>(gt  + base + 4);
        const float4 gC = *reinterpret_cast<const float4*>(gt  + base + 28);
        const float4 gD = *reinterpret_cast<const float4*>(gt  + base + 32);

        // cell 0: coords in A.xyzw, conf in B.x
        float d0 = pA.x - gA.x, d1 = pA.y - gA.y;
        float d2 = pA.z - gA.z, d3 = pA.w - gA.w;
        float dc = pB.x - gB.x;
        float coord0 = d0 * d0 + d1 * d1 + d2 * d2 + d3 * d3;
        float conf0  = dc * dc;
        acc += (gB.x == 1.0f) ? fmaf(5.0f, coord0, 10.0f * conf0) : 0.5f * conf0;

        // cell 1: coords in C.z,C.w,D.x,D.y, conf in D.z
        float e0 = pC.z - gC.z, e1 = pC.w - gC.w;
        float e2 = pD.x - gD.x, e3 = pD.y - gD.y;
        float ec = pD.z - gD.z;
        float coord1 = e0 * e0 + e1 * e1 + e2 * e2 + e3 * e3;
        float conf1  = ec * ec;
        acc += (gD.z == 1.0f) ? fmaf(5.0f, coord1, 10.0f * conf1) : 0.5f * conf1;
    }

    // wave-64 shuffle-down reduction
    for (int offr = 32; offr > 0; offr >>= 1)
        acc += __shfl_down(acc, offr, 64);

    __shared__ float s[4];
    int lane = threadIdx.x & 63;
    int wid  = threadIdx.x >> 6;
    if (lane == 0) s[wid] = acc;
    __syncthreads();

    if (threadIdx.x == 0) {
        float total = s[0] + s[1] + s[2] + s[3];
        atomicAdd(out, total);   // device-scope by default on CDNA
    }
}

extern "C" void kernel_launch(void* const* d_in, const int* in_sizes, int n_in,
                              void* d_out, int out_size, void* d_ws, size_t ws_size,
                              hipStream_t stream) {
    const float* pre = (const float*)d_in[0];
    const float* gt  = (const float*)d_in[1];
    float* out = (float*)d_out;

    // d_out is poisoned once and never re-poisoned between replays: zero it
    // ourselves every call (stream op — graph-capture safe).
    (void)hipMemsetAsync(out, 0, sizeof(float), stream);

    unsigned int n_periods = (unsigned int)((long long)in_sizes[0] / 60);  // 1,605,632

    const int block = 256;
    const int grid  = 2048;   // 8192 waves = max residency; ~3.06 periods/thread
    yolo_loss_kernel<<<grid, block, 0, stream>>>(pre, gt, out, n_periods);
}

// Round 8
// 140.376 us; speedup vs baseline: 1.1148x; 1.0432x over previous
//
#include <hip/hip_runtime.h>

// YOLO loss: per-cell masked squared-error reduction.
// Inputs: label_pre [B,7,7,30] fp32, label_ground_truth [B,7,7,30] fp32.
// Per cell: mask = (gt[...,4] == 1.0)
//   per_cell = mask ? 5*sum((pre[0:4]-gt[0:4])^2) + 10*(pre[4]-gt[4])^2
//                   : 0.5*(pre[4]-gt[4])^2
// Output: scalar sum, shape (1,).
//
// FINAL (= R2, best of 6 structural variants at 139.8 us ~= 5.5 TB/s implied
// on the irreducible 771 MB of line-granular HBM traffic; patterns from
// dense-stream to sparse-chunk all land within +-4%, so this is the HBM
// read-path roofline for this layout).
//
// Layout trick: per 2-cell period (60 floats = 15 aligned float4 chunks),
// the needed channels (0..4 of each cell) live in exactly 4 chunks at
// offsets {0,1,7,8}:
//   chunk +0: cell0 coords 0-3              (comps 0-3)
//   chunk +1: cell0 conf                    (comp 0)
//   chunk +7: cell1 coords 0,1              (comps 2,3)
//   chunk +8: cell1 coords 2,3 + conf       (comps 0,1,2)
// One lane per needed chunk; the cross-chunk mask (gt conf) comes from the
// adjacent lane via __shfl_down(...,1). Role pairs (m%4 = 0/1 and 2/3) never
// straddle a wave boundary (64 % 4 == 0).

__global__ __launch_bounds__(256) void yolo_loss_kernel(
    const float* __restrict__ pre,
    const float* __restrict__ gt,
    float* __restrict__ out,
    long long total_chunks)   // n_cell_pairs * 4
{
    const int role = threadIdx.x & 3;
    // role -> chunk offset within the 15-chunk period: 0,1,7,8
    const int off = (role & 1) + ((role & 2) ? 7 : 0);

    long long tid    = (long long)blockIdx.x * blockDim.x + threadIdx.x;
    long long stride = (long long)gridDim.x * blockDim.x;   // multiple of 4

    float acc = 0.0f;
    for (long long m = tid; m < total_chunks; m += stride) {
        long long q = (m >> 2) * 15 + off;           // float4 chunk index
        const float4 p = *reinterpret_cast<const float4*>(pre + q * 4);
        const float4 g = *reinterpret_cast<const float4*>(gt  + q * 4);

        float d0 = p.x - g.x;
        float d1 = p.y - g.y;
        float d2 = p.z - g.z;
        float d3 = p.w - g.w;

        // neighbor lane's gt values (conf channels live one lane up)
        float gxn = __shfl_down(g.x, 1);   // role0 needs role1's g.x (cell0 conf)
        float gzn = __shfl_down(g.z, 1);   // role2 needs role3's g.z (cell1 conf)

        float c;
        if (role == 0) {
            // cell0 coords 0-3
            c = (gxn == 1.0f) ? 5.0f * (d0*d0 + d1*d1 + d2*d2 + d3*d3) : 0.0f;
        } else if (role == 1) {
            // cell0 conf (local)
            c = (g.x == 1.0f) ? 10.0f * d0*d0 : 0.5f * d0*d0;
        } else if (role == 2) {
            // cell1 coords 0,1 (comps 2,3)
            c = (gzn == 1.0f) ? 5.0f * (d2*d2 + d3*d3) : 0.0f;
        } else {
            // cell1 coords 2,3 (comps 0,1) + conf (comp 2, local)
            c = (g.z == 1.0f) ? 5.0f * (d0*d0 + d1*d1) + 10.0f * d2*d2
                              : 0.5f * d2*d2;
        }
        acc += c;
    }

    // wave-64 shuffle-down reduction
    for (int offr = 32; offr > 0; offr >>= 1)
        acc += __shfl_down(acc, offr, 64);

    __shared__ float s[4];
    int lane = threadIdx.x & 63;
    int wid  = threadIdx.x >> 6;
    if (lane == 0) s[wid] = acc;
    __syncthreads();

    if (threadIdx.x == 0) {
        float total = s[0] + s[1] + s[2] + s[3];
        atomicAdd(out, total);   // device-scope by default on CDNA
    }
}

extern "C" void kernel_launch(void* const* d_in, const int* in_sizes, int n_in,
                              void* d_out, int out_size, void* d_ws, size_t ws_size,
                              hipStream_t stream) {
    const float* pre = (const float*)d_in[0];
    const float* gt  = (const float*)d_in[1];
    float* out = (float*)d_out;

    // d_out is poisoned once and never re-poisoned between replays: zero it
    // ourselves every call (stream op — graph-capture safe).
    (void)hipMemsetAsync(out, 0, sizeof(float), stream);

    long long n_cells = (long long)in_sizes[0] / 30;   // 65536*7*7 = 3,211,264 (even)
    long long total_chunks = (n_cells / 2) * 4;        // 4 needed chunks per cell pair

    const int block = 256;
    const int grid  = 2048;
    yolo_loss_kernel<<<grid, block, 0, stream>>>(pre, gt, out, total_chunks);
}